// Round 7
// baseline (172.386 us; speedup 1.0000x reference)
//
#include <hip/hip_runtime.h>
#include <math.h>

#define T_GRID 2048
#define NC 2048
#define NT 2048
#define BATCH 16
#define XCUT 28.0f        // exp2(-0.72135*28) ~ 2^-20 per-point truncation
#define TILE 128          // output positions per block -> 16 x-tiles exactly
#define SW 144            // staged positions (TILE + 8 halo each side)
#define W 149             // row width: 2 pad + 144 + 2 pad + 1 (149 coprime 32)
#define PCAP 768          // filtered-point LDS capacity (expected ~260)
#define NSB 32            // sub-bins for per-t windowing
#define NBLK 256u
#define MAGIC 0x1234ABCDu

// monotone float<->uint mapping for atomic min/max
__device__ __forceinline__ unsigned mapf(float x) {
    unsigned b = __float_as_uint(x);
    return (b & 0x80000000u) ? ~b : (b | 0x80000000u);
}
__device__ __forceinline__ float unmapf(unsigned u) {
    return (u & 0x80000000u) ? __uint_as_float(u & 0x7fffffffu) : __uint_as_float(~u);
}

// device-scope grid barrier; all NBLK blocks guaranteed co-resident by capacity
__device__ __forceinline__ void gbar(unsigned* ctr) {
    __syncthreads();
    if (threadIdx.x == 0) {
        __threadfence();   // make prior global writes agent-visible (L2 writeback path)
        __hip_atomic_fetch_add(ctr, 1u, __ATOMIC_RELEASE, __HIP_MEMORY_SCOPE_AGENT);
        while (__hip_atomic_load(ctr, __ATOMIC_ACQUIRE, __HIP_MEMORY_SCOPE_AGENT) < NBLK)
            __builtin_amdgcn_s_sleep(1);
        __threadfence();   // acquire: invalidate stale cached lines
    }
    __syncthreads();
}

// =====================================================================
// Single kernel: minmax -> [bar] -> filter/h/conv -> [bar] -> out -> [bar+clean]
// grid 256 x 576. syncv: [0]=flag [1..3]=ctrs [4]=min(mapped) [5]=max(mapped)
// =====================================================================
__global__ __launch_bounds__(576) void k_all(
        const float* __restrict__ xc, const float* __restrict__ yc,
        const float* __restrict__ xt,
        const float* __restrict__ ls_psi, const float* __restrict__ os_psi,
        const float* __restrict__ ls_rho, const float* __restrict__ os_rho,
        const float* __restrict__ w1, const float* __restrict__ b1,
        const float* __restrict__ w2, const float* __restrict__ b2,
        const float* __restrict__ w3, const float* __restrict__ b3,
        const float* __restrict__ w4, const float* __restrict__ b4,
        unsigned* __restrict__ syncv, float* __restrict__ f,
        float2* __restrict__ out) {
    __shared__ float rep[3][W];
    __shared__ float L1s[16][W];                       // layer-1 out; aliased: layer-3 out, phase-3 partials
    __shared__ __align__(16) char pool[32 * W * 4];    // 19072 B: layer-2 out; early: px/py/part/bins; late: smx/ssg
    __shared__ float w1L[15][16];
    __shared__ float w2L[80][32];
    __shared__ float w3L[160][16];
    __shared__ float w4L[80][2];
    __shared__ float bL[66];

    float (*L2s)[W] = reinterpret_cast<float (*)[W]>(pool);
    float (*L3s)[W] = L1s;
    float*  px     = reinterpret_cast<float*>(pool);              // [0, 3072)
    float*  py     = reinterpret_cast<float*>(pool + 3072);       // [3072, 6144)
    float2* part   = reinterpret_cast<float2*>(pool + 6144);      // 576 float2 [6144, 10752)
    int*    bstart = reinterpret_cast<int*>(pool + 10752);        // 33 ints
    int*    curi   = reinterpret_cast<int*>(pool + 10896);        // 32 ints

    int tid = threadIdx.x;
    int bid = blockIdx.x;
    int b = bid >> 4;                 // batch
    int j = bid & 15;                 // x-tile (phase 2) / xt-segment (phase 3)
    int gstart = j * TILE - 8;

    // ---- stage weights/biases (independent; overlaps handshake/minmax) ----
    for (int idx = tid; idx < 240; idx += 576)  { int o = idx / 15,  r2 = idx % 15;  w1L[r2][o] = w1[idx]; }
    for (int idx = tid; idx < 2560; idx += 576) { int o = idx / 80,  r2 = idx % 80;  w2L[r2][o] = w2[idx]; }
    for (int idx = tid; idx < 2560; idx += 576) { int o = idx / 160, r2 = idx % 160; w3L[r2][o] = w3[idx]; }
    for (int idx = tid; idx < 160; idx += 576)  { int o = idx / 80,  r2 = idx % 80;  w4L[r2][o] = w4[idx]; }
    if (tid < 16) bL[tid] = b1[tid];
    if (tid < 32) bL[16 + tid] = b2[tid];
    if (tid < 16) bL[48 + tid] = b3[tid];
    if (tid < 2)  bL[64 + tid] = b4[tid];
    if (tid < 4) {                                     // zero rep/L1 pad cols 0,1,146,147
        int c = (tid < 2) ? tid : tid + SW;
        for (int r2 = 0; r2 < 3; r2++)  rep[r2][c] = 0.f;
        for (int r2 = 0; r2 < 16; r2++) L1s[r2][c] = 0.f;
    }

    // ---- minmax local contribution (loads issue before handshake spin) ----
    float lo = 3.4e38f, hi = -3.4e38f;
    if (tid < 64) {
        const float4* p4 = (tid < 32) ? ((const float4*)xc + bid * 32 + tid)
                                      : ((const float4*)xt + bid * 32 + (tid - 32));
        float4 v = *p4;
        lo = fminf(fminf(v.x, v.y), fminf(v.z, v.w));
        hi = fmaxf(fmaxf(v.x, v.y), fmaxf(v.z, v.w));
    }

    // ---- handshake: leader inits counters+mm, sets flag; all wait for flag ----
    if (tid == 0) {
        if (bid == 0) {
            __hip_atomic_store(&syncv[1], 0u, __ATOMIC_RELAXED, __HIP_MEMORY_SCOPE_AGENT);
            __hip_atomic_store(&syncv[2], 0u, __ATOMIC_RELAXED, __HIP_MEMORY_SCOPE_AGENT);
            __hip_atomic_store(&syncv[3], 0u, __ATOMIC_RELAXED, __HIP_MEMORY_SCOPE_AGENT);
            __hip_atomic_store(&syncv[4], 0xFFFFFFFFu, __ATOMIC_RELAXED, __HIP_MEMORY_SCOPE_AGENT);
            __hip_atomic_store(&syncv[5], 0u, __ATOMIC_RELAXED, __HIP_MEMORY_SCOPE_AGENT);
            __hip_atomic_store(&syncv[0], MAGIC, __ATOMIC_RELEASE, __HIP_MEMORY_SCOPE_AGENT);
        }
        while (__hip_atomic_load(&syncv[0], __ATOMIC_ACQUIRE, __HIP_MEMORY_SCOPE_AGENT) != MAGIC)
            __builtin_amdgcn_s_sleep(1);
    }
    __syncthreads();

    // ---- minmax: wave-reduce + device atomics ----
    if (tid < 64) {
        for (int off = 32; off; off >>= 1) {
            lo = fminf(lo, __shfl_down(lo, off));
            hi = fmaxf(hi, __shfl_down(hi, off));
        }
        if (tid == 0) {
            atomicMin(&syncv[4], mapf(lo));
            atomicMax(&syncv[5], mapf(hi));
        }
    }
    gbar(&syncv[1]);

    float lower = unmapf(__hip_atomic_load(&syncv[4], __ATOMIC_RELAXED, __HIP_MEMORY_SCOPE_AGENT));
    float upper = unmapf(__hip_atomic_load(&syncv[5], __ATOMIC_RELAXED, __HIP_MEMORY_SCOPE_AGENT));
    float step = (upper - lower) * (1.0f / (T_GRID - 1));

    // =========================== phase 2: h + conv ===========================
    {
        float ls = ls_psi[0], os = os_psi[0];
        float c2 = -0.72134752044f / (ls * ls);        // -0.5*log2(e)/ls^2
        float R = ls * sqrtf(XCUT);

        int g0 = max(gstart, 0), g1 = min(gstart + SW - 1, T_GRID - 1);
        float tmin = fmaf((float)g0, step, lower) - R;
        float tmax = fmaf((float)g1, step, lower) + R;
        float sbw_inv = (float)NSB / (tmax - tmin);

        // filter own batch's points into tile box, bucket into NSB sub-bins
        if (tid < NSB + 1) bstart[tid] = 0;
        __syncthreads();
        float xv[4], yv[4];
        int bn[4];
        const float* xb = xc + b * NC;
        const float* yb = yc + b * NC;
#pragma unroll
        for (int k = 0; k < 4; k++) {
            int idx = tid + 576 * k;
            bn[k] = -1;
            if (idx < NC) {
                xv[k] = xb[idx];
                yv[k] = yb[idx];
                if ((xv[k] >= tmin) & (xv[k] <= tmax)) {
                    bn[k] = min(NSB - 1, max(0, (int)((xv[k] - tmin) * sbw_inv)));
                    atomicAdd(&bstart[bn[k]], 1);
                }
            }
        }
        __syncthreads();
        if (tid == 0) {
            int run = 0;
            for (int i = 0; i < NSB; i++) { int c = bstart[i]; bstart[i] = run; run += c; }
            bstart[NSB] = run;
        }
        __syncthreads();
        if (tid < NSB) curi[tid] = bstart[tid];
        __syncthreads();
#pragma unroll
        for (int k = 0; k < 4; k++) {
            if (bn[k] >= 0) {
                int pos = atomicAdd(&curi[bn[k]], 1);
                if (pos < PCAP) { px[pos] = xv[k]; py[pos] = yv[k]; }
            }
        }
        __syncthreads();

        // h-phase: 4 threads per staged position (576 = 4 x 144)
        {
            int p = tid >> 2, rr = tid & 3;
            int gp = gstart + p;
            bool pvalid = (gp >= 0 && gp < T_GRID);
            float t = fmaf((float)gp, step, lower);
            int s = 0, e = 0;
            if (pvalid) {
                int b0 = min(NSB - 1, max(0, (int)((t - R - tmin) * sbw_inv)));
                int b1i = min(NSB - 1, max(0, (int)((t + R - tmin) * sbw_inv)));
                s = bstart[b0];
                e = min(bstart[b1i + 1], PCAP);
            }
            float S0 = 0.f, S1 = 0.f;
            for (int jj = s + rr; jj < e; jj += 4) {
                float xj = px[jj], yj = py[jj];
                float d = t - xj;
                float ev = exp2f(d * d * c2);
                S0 += ev;
                S1 = fmaf(ev, yj, S1);
            }
            part[rr * SW + p] = make_float2(S0, S1);
            __syncthreads();
            if (tid < SW) {
                float2 q0 = part[tid], q1 = part[tid + SW], q2 = part[tid + 2 * SW], q3 = part[tid + 3 * SW];
                float T0 = q0.x + q1.x + q2.x + q3.x;
                float T1 = q0.y + q1.y + q2.y + q3.y;
                int gp2 = gstart + tid;
                bool pv2 = (gp2 >= 0 && gp2 < T_GRID);
                float h0 = os * T0;
                float h1 = os * T1 / (h0 + 1e-8f);
                rep[0][tid + 2] = pv2 ? fmaf((float)gp2, step, lower) : 0.f;
                rep[1][tid + 2] = pv2 ? h0 : 0.f;
                rep[2][tid + 2] = pv2 ? h1 : 0.f;
            }
        }
        __syncthreads();

        // layer 1: 3 -> 16, relu
        {
            if (tid < 4) {
                int c = (tid < 2) ? tid : tid + SW;
                for (int r2 = 0; r2 < 32; r2++) L2s[r2][c] = 0.f;
            }
            int o = tid & 15, s0 = (tid >> 4) << 2;
            float acc[4];
            float bias = bL[o];
#pragma unroll
            for (int s = 0; s < 4; s++) acc[s] = bias;
            for (int i = 0; i < 3; i++) {
                float x[8];
#pragma unroll
                for (int jj = 0; jj < 8; jj++) x[jj] = rep[i][s0 + jj];
#pragma unroll
                for (int k = 0; k < 5; k++) {
                    float w = w1L[i * 5 + k][o];
#pragma unroll
                    for (int s = 0; s < 4; s++) acc[s] = fmaf(x[s + k], w, acc[s]);
                }
            }
#pragma unroll
            for (int s = 0; s < 4; s++) {
                int p = s0 + s, gp = gstart + p;
                bool vv = (p >= 2 && p < SW - 2 && gp >= 0 && gp < T_GRID);
                L1s[o][p + 2] = vv ? fmaxf(acc[s], 0.f) : 0.f;
            }
        }
        __syncthreads();

        // layer 2: 16 -> 32, relu
        {
            int o = tid & 31, s0 = (tid >> 5) << 3;
            float acc[8];
            float bias = bL[16 + o];
#pragma unroll
            for (int s = 0; s < 8; s++) acc[s] = bias;
            for (int i = 0; i < 16; i++) {
                float x[12];
#pragma unroll
                for (int jj = 0; jj < 12; jj++) x[jj] = L1s[i][s0 + jj];
#pragma unroll
                for (int k = 0; k < 5; k++) {
                    float w = w2L[i * 5 + k][o];
#pragma unroll
                    for (int s = 0; s < 8; s++) acc[s] = fmaf(x[s + k], w, acc[s]);
                }
            }
#pragma unroll
            for (int s = 0; s < 8; s++) {
                int p = s0 + s, gp = gstart + p;
                bool vv = (p >= 4 && p < SW - 4 && gp >= 0 && gp < T_GRID);
                L2s[o][p + 2] = vv ? fmaxf(acc[s], 0.f) : 0.f;
            }
        }
        __syncthreads();

        // layer 3: 32 -> 16, relu (writes into dead L1 alias)
        {
            int o = tid & 15, s0 = (tid >> 4) << 2;
            float acc[4];
            float bias = bL[48 + o];
#pragma unroll
            for (int s = 0; s < 4; s++) acc[s] = bias;
            for (int i = 0; i < 32; i++) {
                float x[8];
#pragma unroll
                for (int jj = 0; jj < 8; jj++) x[jj] = L2s[i][s0 + jj];
#pragma unroll
                for (int k = 0; k < 5; k++) {
                    float w = w3L[i * 5 + k][o];
#pragma unroll
                    for (int s = 0; s < 4; s++) acc[s] = fmaf(x[s + k], w, acc[s]);
                }
            }
#pragma unroll
            for (int s = 0; s < 4; s++) {
                int p = s0 + s, gp = gstart + p;
                bool vv = (p >= 6 && p < SW - 6 && gp >= 0 && gp < T_GRID);
                L3s[o][p + 2] = vv ? fmaxf(acc[s], 0.f) : 0.f;
            }
        }
        __syncthreads();

        // layer 4: 16 -> 2 + softplus; threads 0..255
        if (tid < 256) {
            int o = tid & 1, po = tid >> 1;
            float a = bL[64 + o];
            for (int i = 0; i < 16; i++) {
#pragma unroll
                for (int k = 0; k < 5; k++) {
                    a = fmaf(L3s[i][po + 8 + k], w4L[i * 5 + k][o], a);
                }
            }
            int gp = j * TILE + po;
            if (o) {
                float sp = fmaxf(a, 0.f) + log1pf(expf(-fabsf(a)));
                f[2 * (b * T_GRID + gp) + 1] = sp;
            } else {
                f[2 * (b * T_GRID + gp)] = a;
            }
        }
    }
    gbar(&syncv[2]);    // f fully written & agent-visible

    // =========================== phase 3: output RBF ===========================
    {
        float* smx = reinterpret_cast<float*>(pool);              // 8 KB
        float* ssg = reinterpret_cast<float*>(pool + 8192);       // 8 KB
        float2* part3 = reinterpret_cast<float2*>(&L1s[0][0]);    // 4 KB (L1s is 9.5 KB)

        float ls = ls_rho[0], os = os_rho[0];
        float c2 = -0.72134752044f / (ls * ls);
        float R = ls * sqrtf(XCUT);
        float invstep = 1.0f / step;

        const float2* fb = (const float2*)f + b * T_GRID;
        for (int k = tid; k < T_GRID; k += 576) {
            float2 v = fb[k];
            smx[k] = v.x; ssg[k] = v.y;
        }
        __syncthreads();

        float Smu = 0.f, Ssg = 0.f;
        int q = tid >> 2, rr = tid & 3;
        if (tid < 512) {
            float x = xt[b * NT + j * 128 + q];
            int j0 = max(0, (int)floorf((x - R - lower) * invstep));
            int j1 = min(T_GRID - 1, (int)ceilf((x + R - lower) * invstep));
            float jf = (float)(j0 + rr);
            for (int jj = j0 + rr; jj <= j1; jj += 4) {
                float d = x - fmaf(jf, step, lower);
                float e = exp2f(d * d * c2);
                Smu = fmaf(e, smx[jj], Smu);
                Ssg = fmaf(e, ssg[jj], Ssg);
                jf += 4.0f;
            }
            part3[rr * 128 + q] = make_float2(Smu, Ssg);
        }
        __syncthreads();
        if (tid < 128) {
            float2 p0 = part3[tid], p1 = part3[128 + tid], p2 = part3[256 + tid], p3 = part3[384 + tid];
            float sm = p0.x + p1.x + p2.x + p3.x;
            float sg = p0.y + p1.y + p2.y + p3.y;
            out[b * NT + j * 128 + tid] = make_float2(os * sm, os * sg);
        }
    }

    // ---- cleanup barrier: flag reset works even without harness re-poison ----
    gbar(&syncv[3]);
    if (bid == 0 && tid == 0)
        __hip_atomic_store(&syncv[0], 0u, __ATOMIC_RELAXED, __HIP_MEMORY_SCOPE_AGENT);
}

// ---------- launcher ----------
extern "C" void kernel_launch(void* const* d_in, const int* in_sizes, int n_in,
                              void* d_out, int out_size, void* d_ws, size_t ws_size,
                              hipStream_t stream) {
    const float* xc = (const float*)d_in[0];
    const float* yc = (const float*)d_in[1];
    const float* xt = (const float*)d_in[2];
    const float* ls_psi = (const float*)d_in[3];
    const float* os_psi = (const float*)d_in[4];
    const float* ls_rho = (const float*)d_in[5];
    const float* os_rho = (const float*)d_in[6];
    const float* w1 = (const float*)d_in[7];
    const float* b1 = (const float*)d_in[8];
    const float* w2 = (const float*)d_in[9];
    const float* b2 = (const float*)d_in[10];
    const float* w3 = (const float*)d_in[11];
    const float* b3 = (const float*)d_in[12];
    const float* w4 = (const float*)d_in[13];
    const float* b4 = (const float*)d_in[14];

    char* ws = (char*)d_ws;
    unsigned* syncv = (unsigned*)ws;           // 8 words
    float* f = (float*)(ws + 256);             // 256 KB

    k_all<<<dim3(NBLK), dim3(576), 0, stream>>>(
        xc, yc, xt, ls_psi, os_psi, ls_rho, os_rho,
        w1, b1, w2, b2, w3, b3, w4, b4,
        syncv, f, (float2*)d_out);
}

// Round 8
// 106.024 us; speedup vs baseline: 1.6259x; 1.6259x over previous
//
#include <hip/hip_runtime.h>
#include <math.h>

#define T_GRID 2048
#define NC 2048
#define NT 2048
#define BATCH 16
#define XCUT 28.0f        // exp2(-0.72135*28) ~ 2^-20 per-point truncation
#define TILE 128          // output positions per block -> 16 x-tiles exactly
#define SW 144            // staged positions (TILE + 8 halo each side)
#define W 149             // row width: 2 pad + 144 + 2 pad + 1 (149 coprime 32)
#define PCAP 768          // filtered-point LDS capacity (expected ~260)
#define NSB 32            // sub-bins for per-t windowing
#define NMMB 16           // minmax partial blocks

// merge the 16 partial (min,max) slots; uniform address -> scalar loads
__device__ __forceinline__ float2 merge_slots(const float2* __restrict__ slots) {
    float lo = 3.4e38f, hi = -3.4e38f;
#pragma unroll
    for (int i = 0; i < NMMB; i++) {
        float2 s = slots[i];
        lo = fminf(lo, s.x);
        hi = fmaxf(hi, s.y);
    }
    return make_float2(lo, hi);
}

// =====================================================================
// K1: 16-block partial min/max; block i writes slots[i]. No atomics/init.
// =====================================================================
__global__ __launch_bounds__(256) void k_minmax16(const float4* __restrict__ xc4,
                                                  const float4* __restrict__ xt4,
                                                  float2* __restrict__ slots) {
    int tid = threadIdx.x, bid = blockIdx.x;
    float lo = 3.4e38f, hi = -3.4e38f;
    int base = bid * 512 + tid;
#pragma unroll
    for (int k = 0; k < 2; k++) {
        float4 a = xc4[base + 256 * k];
        float4 b = xt4[base + 256 * k];
        lo = fminf(lo, fminf(fminf(a.x, a.y), fminf(a.z, a.w)));
        hi = fmaxf(hi, fmaxf(fmaxf(a.x, a.y), fmaxf(a.z, a.w)));
        lo = fminf(lo, fminf(fminf(b.x, b.y), fminf(b.z, b.w)));
        hi = fmaxf(hi, fmaxf(fmaxf(b.x, b.y), fmaxf(b.z, b.w)));
    }
    for (int off = 32; off; off >>= 1) {
        lo = fminf(lo, __shfl_down(lo, off));
        hi = fmaxf(hi, __shfl_down(hi, off));
    }
    __shared__ float slo[4], shi[4];
    int lane = tid & 63, wv = tid >> 6;
    if (lane == 0) { slo[wv] = lo; shi[wv] = hi; }
    __syncthreads();
    if (tid == 0) {
        for (int w = 1; w < 4; w++) { lo = fminf(lo, slo[w]); hi = fmaxf(hi, shi[w]); }
        slots[bid] = make_float2(lo, hi);
    }
}

// =====================================================================
// K2: fused filter+bucket -> h (RBF smoother) -> conv x4.  576 threads.
// grid (16, 16) = 256 blocks = 1/CU. Writes f (float2 per grid point).
// =====================================================================
__global__ __launch_bounds__(576) void k_fused(
        const float* __restrict__ xc, const float* __restrict__ yc,
        const float* __restrict__ ls_psi, const float* __restrict__ os_psi,
        const float2* __restrict__ slots,
        const float* __restrict__ w1, const float* __restrict__ b1,
        const float* __restrict__ w2, const float* __restrict__ b2,
        const float* __restrict__ w3, const float* __restrict__ b3,
        const float* __restrict__ w4, const float* __restrict__ b4,
        float* __restrict__ f) {
    __shared__ float rep[3][W];
    __shared__ float L1s[16][W];                       // layer-1 out; aliased as layer-3 out
    __shared__ __align__(16) char pool[32 * W * 4];    // 19072 B: layer-2 out; early: px/py/part/bins
    __shared__ float w1L[15][16];
    __shared__ float w2L[80][32];
    __shared__ float w3L[160][16];
    __shared__ float w4L[80][2];
    __shared__ float bL[66];

    float (*L2s)[W] = reinterpret_cast<float (*)[W]>(pool);
    float (*L3s)[W] = L1s;
    float*  px     = reinterpret_cast<float*>(pool);              // [0, 3072)
    float*  py     = reinterpret_cast<float*>(pool + 3072);       // [3072, 6144)
    float2* part   = reinterpret_cast<float2*>(pool + 6144);      // 576 float2 [6144, 10752)
    int*    bstart = reinterpret_cast<int*>(pool + 10752);        // 33 ints
    int*    curi   = reinterpret_cast<int*>(pool + 10896);        // 32 ints

    int tid = threadIdx.x;
    int b = blockIdx.y;
    int gstart = blockIdx.x * TILE - 8;                // staged gp = gstart + p, p in [0,SW)

    // ---- stage weights/biases ----
    for (int idx = tid; idx < 240; idx += 576)  { int o = idx / 15,  r2 = idx % 15;  w1L[r2][o] = w1[idx]; }
    for (int idx = tid; idx < 2560; idx += 576) { int o = idx / 80,  r2 = idx % 80;  w2L[r2][o] = w2[idx]; }
    for (int idx = tid; idx < 2560; idx += 576) { int o = idx / 160, r2 = idx % 160; w3L[r2][o] = w3[idx]; }
    for (int idx = tid; idx < 160; idx += 576)  { int o = idx / 80,  r2 = idx % 80;  w4L[r2][o] = w4[idx]; }
    if (tid < 16) bL[tid] = b1[tid];
    if (tid < 32) bL[16 + tid] = b2[tid];
    if (tid < 16) bL[48 + tid] = b3[tid];
    if (tid < 2)  bL[64 + tid] = b4[tid];
    if (tid < 4) {                                     // zero rep/L1 pad cols 0,1,146,147
        int c = (tid < 2) ? tid : tid + SW;
        for (int r2 = 0; r2 < 3; r2++)  rep[r2][c] = 0.f;
        for (int r2 = 0; r2 < 16; r2++) L1s[r2][c] = 0.f;
    }

    float2 lu = merge_slots(slots);
    float lower = lu.x, upper = lu.y;
    float step = (upper - lower) * (1.0f / (T_GRID - 1));
    float ls = ls_psi[0], os = os_psi[0];
    float c2 = -0.72134752044f / (ls * ls);            // -0.5*log2(e)/ls^2
    float R = ls * sqrtf(XCUT);

    int g0 = max(gstart, 0), g1 = min(gstart + SW - 1, T_GRID - 1);
    float tmin = fmaf((float)g0, step, lower) - R;
    float tmax = fmaf((float)g1, step, lower) + R;
    float sbw_inv = (float)NSB / (tmax - tmin);

    // ---- filter own batch's points into tile box, bucket into NSB sub-bins ----
    // y is loaded lazily: only for in-box points (~13%)
    if (tid < NSB + 1) bstart[tid] = 0;
    __syncthreads();
    float xv[4], yv[4];
    int bn[4];
    const float* xb = xc + b * NC;
    const float* yb = yc + b * NC;
#pragma unroll
    for (int k = 0; k < 4; k++) {
        int idx = tid + 576 * k;
        bn[k] = -1;
        if (idx < NC) {
            xv[k] = xb[idx];
            if ((xv[k] >= tmin) & (xv[k] <= tmax)) {
                bn[k] = min(NSB - 1, max(0, (int)((xv[k] - tmin) * sbw_inv)));
                yv[k] = yb[idx];                       // predicated load, issues here
                atomicAdd(&bstart[bn[k]], 1);
            }
        }
    }
    __syncthreads();
    if (tid == 0) {
        int run = 0;
        for (int i = 0; i < NSB; i++) { int c = bstart[i]; bstart[i] = run; run += c; }
        bstart[NSB] = run;
    }
    __syncthreads();
    if (tid < NSB) curi[tid] = bstart[tid];
    __syncthreads();
#pragma unroll
    for (int k = 0; k < 4; k++) {
        if (bn[k] >= 0) {
            int pos = atomicAdd(&curi[bn[k]], 1);
            if (pos < PCAP) { px[pos] = xv[k]; py[pos] = yv[k]; }
        }
    }
    __syncthreads();

    // ---- h-phase: 4 threads per staged position (576 = 4 x 144) ----
    {
        int p = tid >> 2, rr = tid & 3;                // p in [0,144)
        int gp = gstart + p;
        bool pvalid = (gp >= 0 && gp < T_GRID);
        float t = fmaf((float)gp, step, lower);
        int s = 0, e = 0;
        if (pvalid) {
            int b0 = min(NSB - 1, max(0, (int)((t - R - tmin) * sbw_inv)));
            int b1i = min(NSB - 1, max(0, (int)((t + R - tmin) * sbw_inv)));
            s = bstart[b0];
            e = min(bstart[b1i + 1], PCAP);
        }
        float S0 = 0.f, S1 = 0.f;
        for (int j = s + rr; j < e; j += 4) {
            float xj = px[j], yj = py[j];
            float d = t - xj;
            float ev = exp2f(d * d * c2);
            S0 += ev;
            S1 = fmaf(ev, yj, S1);
        }
        part[rr * SW + p] = make_float2(S0, S1);       // disjoint from px/py
        __syncthreads();
        if (tid < SW) {
            float2 q0 = part[tid], q1 = part[tid + SW], q2 = part[tid + 2 * SW], q3 = part[tid + 3 * SW];
            float T0 = q0.x + q1.x + q2.x + q3.x;
            float T1 = q0.y + q1.y + q2.y + q3.y;
            int gp2 = gstart + tid;
            bool pv2 = (gp2 >= 0 && gp2 < T_GRID);
            float h0 = os * T0;
            float h1 = os * T1 / (h0 + 1e-8f);
            rep[0][tid + 2] = pv2 ? fmaf((float)gp2, step, lower) : 0.f;
            rep[1][tid + 2] = pv2 ? h0 : 0.f;
            rep[2][tid + 2] = pv2 ? h1 : 0.f;
        }
    }
    __syncthreads();                                   // pool (px/py/part/bins) dead now

    // ---- layer 1: 3 -> 16, relu. o=tid&15, 36 groups x strip 4 ----
    {
        if (tid < 4) {                                 // zero L2 pad cols
            int c = (tid < 2) ? tid : tid + SW;
            for (int r2 = 0; r2 < 32; r2++) L2s[r2][c] = 0.f;
        }
        int o = tid & 15, s0 = (tid >> 4) << 2;        // s0 in {0,4,...,140}
        float acc[4];
        float bias = bL[o];
#pragma unroll
        for (int s = 0; s < 4; s++) acc[s] = bias;
        for (int i = 0; i < 3; i++) {
            float x[8];
#pragma unroll
            for (int j = 0; j < 8; j++) x[j] = rep[i][s0 + j];
#pragma unroll
            for (int k = 0; k < 5; k++) {
                float w = w1L[i * 5 + k][o];
#pragma unroll
                for (int s = 0; s < 4; s++) acc[s] = fmaf(x[s + k], w, acc[s]);
            }
        }
#pragma unroll
        for (int s = 0; s < 4; s++) {
            int p = s0 + s, gp = gstart + p;
            bool vv = (p >= 2 && p < SW - 2 && gp >= 0 && gp < T_GRID);
            L1s[o][p + 2] = vv ? fmaxf(acc[s], 0.f) : 0.f;
        }
    }
    __syncthreads();

    // ---- layer 2: 16 -> 32, relu. o=tid&31, 18 groups x strip 8 ----
    {
        int o = tid & 31, s0 = (tid >> 5) << 3;        // s0 in {0,8,...,136}
        float acc[8];
        float bias = bL[16 + o];
#pragma unroll
        for (int s = 0; s < 8; s++) acc[s] = bias;
        for (int i = 0; i < 16; i++) {
            float x[12];
#pragma unroll
            for (int j = 0; j < 12; j++) x[j] = L1s[i][s0 + j];
#pragma unroll
            for (int k = 0; k < 5; k++) {
                float w = w2L[i * 5 + k][o];
#pragma unroll
                for (int s = 0; s < 8; s++) acc[s] = fmaf(x[s + k], w, acc[s]);
            }
        }
#pragma unroll
        for (int s = 0; s < 8; s++) {
            int p = s0 + s, gp = gstart + p;
            bool vv = (p >= 4 && p < SW - 4 && gp >= 0 && gp < T_GRID);
            L2s[o][p + 2] = vv ? fmaxf(acc[s], 0.f) : 0.f;
        }
    }
    __syncthreads();

    // ---- layer 3: 32 -> 16, relu. writes into L1 storage (dead alias) ----
    {
        int o = tid & 15, s0 = (tid >> 4) << 2;
        float acc[4];
        float bias = bL[48 + o];
#pragma unroll
        for (int s = 0; s < 4; s++) acc[s] = bias;
        for (int i = 0; i < 32; i++) {
            float x[8];
#pragma unroll
            for (int j = 0; j < 8; j++) x[j] = L2s[i][s0 + j];
#pragma unroll
            for (int k = 0; k < 5; k++) {
                float w = w3L[i * 5 + k][o];
#pragma unroll
                for (int s = 0; s < 4; s++) acc[s] = fmaf(x[s + k], w, acc[s]);
            }
        }
#pragma unroll
        for (int s = 0; s < 4; s++) {
            int p = s0 + s, gp = gstart + p;
            bool vv = (p >= 6 && p < SW - 6 && gp >= 0 && gp < T_GRID);
            L3s[o][p + 2] = vv ? fmaxf(acc[s], 0.f) : 0.f;
        }
    }
    __syncthreads();

    // ---- layer 4: 16 -> 2 + softplus; threads 0..255, outputs land on [0,T) ----
    if (tid < 256) {
        int o = tid & 1, po = tid >> 1;                // po in [0,128)
        float a = bL[64 + o];
        for (int i = 0; i < 16; i++) {
#pragma unroll
            for (int k = 0; k < 5; k++) {
                a = fmaf(L3s[i][po + 8 + k], w4L[i * 5 + k][o], a);
            }
        }
        int gp = blockIdx.x * TILE + po;               // in [0,2048) always
        if (o) {
            float sp = fmaxf(a, 0.f) + log1pf(expf(-fabsf(a)));
            f[2 * (b * T_GRID + gp) + 1] = sp;
        } else {
            f[2 * (b * T_GRID + gp)] = a;
        }
    }
}

// =====================================================================
// K3: windowed out = RBF(xt, t) @ [f_mu, f_sp], 4 threads per xt
// =====================================================================
__global__ __launch_bounds__(256) void k_out(const float* __restrict__ xt,
                                             const float* __restrict__ ls_rho,
                                             const float* __restrict__ os_rho,
                                             const float2* __restrict__ slots,
                                             const float2* __restrict__ f,
                                             float2* __restrict__ out) {
    __shared__ float smx[T_GRID];
    __shared__ float ssg[T_GRID];
    __shared__ float2 part[256];
    int b = blockIdx.y, tid = threadIdx.x;
    int it = blockIdx.x * 64 + (tid & 63);
    int r = tid >> 6;
    float2 lu = merge_slots(slots);
    float lower = lu.x, upper = lu.y;
    float step = (upper - lower) * (1.0f / (T_GRID - 1));
    float invstep = 1.0f / step;
    float ls = ls_rho[0], os = os_rho[0];
    float c2 = -0.72134752044f / (ls * ls);
    float R = ls * sqrtf(XCUT);
    float x = xt[b * NT + it];

    const float2* fb = f + b * T_GRID;
    for (int k = tid; k < T_GRID; k += 256) {
        float2 v = fb[k];
        smx[k] = v.x; ssg[k] = v.y;
    }
    __syncthreads();

    int j0 = max(0, (int)floorf((x - R - lower) * invstep));
    int j1 = min(T_GRID - 1, (int)ceilf((x + R - lower) * invstep));

    float Smu = 0.f, Ssg = 0.f;
    float jf = (float)(j0 + r);
    for (int j = j0 + r; j <= j1; j += 4) {
        float d = x - fmaf(jf, step, lower);
        float e = exp2f(d * d * c2);
        Smu = fmaf(e, smx[j], Smu);
        Ssg = fmaf(e, ssg[j], Ssg);
        jf += 4.0f;
    }
    part[tid] = make_float2(Smu, Ssg);
    __syncthreads();
    if (r == 0) {
#pragma unroll
        for (int q = 64; q < 256; q += 64) {
            float2 pp = part[tid + q];
            Smu += pp.x; Ssg += pp.y;
        }
        out[b * NT + it] = make_float2(os * Smu, os * Ssg);
    }
}

// ---------- launcher ----------
extern "C" void kernel_launch(void* const* d_in, const int* in_sizes, int n_in,
                              void* d_out, int out_size, void* d_ws, size_t ws_size,
                              hipStream_t stream) {
    const float* xc = (const float*)d_in[0];
    const float* yc = (const float*)d_in[1];
    const float* xt = (const float*)d_in[2];
    const float* ls_psi = (const float*)d_in[3];
    const float* os_psi = (const float*)d_in[4];
    const float* ls_rho = (const float*)d_in[5];
    const float* os_rho = (const float*)d_in[6];
    const float* w1 = (const float*)d_in[7];
    const float* b1 = (const float*)d_in[8];
    const float* w2 = (const float*)d_in[9];
    const float* b2 = (const float*)d_in[10];
    const float* w3 = (const float*)d_in[11];
    const float* b3 = (const float*)d_in[12];
    const float* w4 = (const float*)d_in[13];
    const float* b4 = (const float*)d_in[14];

    char* ws = (char*)d_ws;
    float2* slots = (float2*)ws;               // 16 float2 = 128 B
    float* f = (float*)(ws + 256);             // 256 KB

    k_minmax16<<<dim3(NMMB), dim3(256), 0, stream>>>((const float4*)xc, (const float4*)xt, slots);

    k_fused<<<dim3(T_GRID / TILE, BATCH), dim3(576), 0, stream>>>(
        xc, yc, ls_psi, os_psi, slots,
        w1, b1, w2, b2, w3, b3, w4, b4, f);

    k_out<<<dim3(NT / 64, BATCH), dim3(256), 0, stream>>>(
        xt, ls_rho, os_rho, slots, (const float2*)f, (float2*)d_out);
}